// Round 13
// baseline (213.179 us; speedup 1.0000x reference)
//
#include <hip/hip_runtime.h>
#include <math.h>

// L=4096, N=16, H=16, E=64. rho = L*N = 65536 rows of 1024 floats (head h at +64h).
// out[rho][h][f] = exp2( x.Ps[h][:,f] - sq*SQS ) + 1e-6, Ps = proj*64^-.25*log2e.
// proj = q^T D, D = sign(diag(r)) of LAPACK-convention QR(pm[h]^T) (convention-
// dependent — must reproduce geqrf signs). Factor then Q = M R^-1.
// favor: f16 hi/lo split MFMA (C = Xh*Bh + Xh*Bl + Xl*Bh), residual ~2^-23.
// Round-13: 8 heads per 512-thread block -> 2-KB contiguous segments per row
// (read AND write) instead of 256-B. r3-r12 all plateaued at 150-177us with
// 256-B @ 4-KB-stride streams at ~3.4 TB/s effective; contiguity is the one
// untried axis (fillBuffer sustains 7 TB/s contiguous on this machine).

typedef _Float16 f16x8 __attribute__((ext_vector_type(8)));
typedef float    f32x4 __attribute__((ext_vector_type(4)));

#define AS1 __attribute__((address_space(1)))
#define AS3 __attribute__((address_space(3)))

#if __has_builtin(__builtin_amdgcn_exp2f)
#define EXP2F(x) __builtin_amdgcn_exp2f(x)
#else
#define EXP2F(x) exp2f(x)
#endif

static __device__ __forceinline__ void gload16(const float* g, float* l) {
    __builtin_amdgcn_global_load_lds((AS1 const void*)g, (AS3 void*)l, 16, 0, 0);
}

// ---------------- per-head QR (fp32 Householder, LAPACK dlarfg signs) -------
__global__ __launch_bounds__(256) void qr_kernel(const float* __restrict__ pm,
                                                 float* __restrict__ P)
{
    __shared__ float colb[2][64];
    __shared__ float nrmb[2];
    __shared__ float Rs[64 * 65];
    __shared__ float qcol[2][64];
    __shared__ float dval[64];
    __shared__ float dinv[64];
    __shared__ float sgnNZ[64];

    const int tid = threadIdx.x;
    const int h   = blockIdx.x;
    const int c   = tid >> 2;       // column 0..63 (quad = 4 consecutive lanes)
    const int q   = tid & 3;        // row-quarter
    const int i0  = q * 16;

    float A[16], M[16];             // A[k] = M[i0+k][c] = pm[h][c][i0+k]
    {
        const float4* src = reinterpret_cast<const float4*>(pm + h * 4096 + c * 64 + i0);
        #pragma unroll
        for (int k4 = 0; k4 < 4; ++k4) {
            const float4 v = src[k4];
            A[4*k4+0] = M[4*k4+0] = v.x;
            A[4*k4+1] = M[4*k4+1] = v.y;
            A[4*k4+2] = M[4*k4+2] = v.z;
            A[4*k4+3] = M[4*k4+3] = v.w;
        }
    }
    if (c == 0) {                    // publish column 0 + its sub-norm
        #pragma unroll
        for (int k = 0; k < 16; ++k) colb[0][i0 + k] = A[k];
        float np = 0.f;
        #pragma unroll
        for (int k = 0; k < 16; ++k) if (i0 + k >= 1) np = fmaf(A[k], A[k], np);
        np += __shfl_xor(np, 1); np += __shfl_xor(np, 2);
        if (q == 0) nrmb[0] = np;
    }
    __syncthreads();

    // ---- factor: 64 Householder steps, 1 barrier each ----
    #pragma unroll 1
    for (int j = 0; j < 64; ++j) {
        const float* cbuf = colb[j & 1];
        const float alpha = cbuf[j];
        const float nrm2  = nrmb[j & 1];
        float beta, g;
        if (nrm2 == 0.f) { beta = alpha; g = 0.f; }          // H = I, tau = 0
        else {
            const float an = sqrtf(fmaf(alpha, alpha, nrm2));
            beta = (alpha >= 0.f) ? -an : an;                // -sign(alpha)*norm
            g    = 1.f / (beta * (beta - alpha));            // tau/(alpha-beta)^2
        }
        if (c >= j) {
            float cb[16];
            #pragma unroll
            for (int k = 0; k < 16; ++k) cb[k] = cbuf[i0 + k];
            float wp = 0.f, Ajc = 0.f;
            #pragma unroll
            for (int k = 0; k < 16; ++k) {
                const int i = i0 + k;
                wp  = fmaf((i > j) ? cb[k] : 0.f, A[k], wp); // v0 (i>j) part
                Ajc += (i == j) ? A[k] : 0.f;                // A[j][c]
            }
            wp  += __shfl_xor(wp, 1);  wp  += __shfl_xor(wp, 2);
            Ajc += __shfl_xor(Ajc, 1); Ajc += __shfl_xor(Ajc, 2);
            const float amb = alpha - beta;
            const float gw  = g * (wp + amb * Ajc);          // g * v0^T A[:,c]
            #pragma unroll
            for (int k = 0; k < 16; ++k) {
                const int i = i0 + k;
                const float v0 = (i > j) ? cb[k] : ((i == j) ? amb : 0.f);
                A[k] = fmaf(-gw, v0, A[k]);
            }
            if (c == j + 1) {        // publish next column into the OTHER buffer
                #pragma unroll
                for (int k = 0; k < 16; ++k) colb[(j + 1) & 1][i0 + k] = A[k];
                float np = 0.f;
                #pragma unroll
                for (int k = 0; k < 16; ++k) {
                    const int i = i0 + k;
                    np = fmaf((i > j + 1) ? A[k] : 0.f, A[k], np);
                }
                np += __shfl_xor(np, 1); np += __shfl_xor(np, 2);
                if (q == 0) nrmb[(j + 1) & 1] = np;
            }
        }
        __syncthreads();
    }

    // ---- R to LDS, diag inverses/signs, qcol prologue ----
    #pragma unroll
    for (int k = 0; k < 16; ++k) Rs[(i0 + k) * 65 + c] = A[k];
    {
        float dv = 0.f;
        #pragma unroll
        for (int k = 0; k < 16; ++k) dv += (i0 + k == c) ? A[k] : 0.f;
        dv += __shfl_xor(dv, 1); dv += __shfl_xor(dv, 2);
        if (q == 0) dval[c] = dv;
    }
    if (c == 0) {
        #pragma unroll
        for (int k = 0; k < 16; ++k) qcol[0][i0 + k] = M[k];
    }
    __syncthreads();
    if (tid < 64) {
        const float d = dval[tid];
        dinv[tid] = 1.f / d;
        const float NZL2E = 0.51012934f;     // 64^-0.25 * log2(e)
        sgnNZ[tid] = (d >= 0.f) ? NZL2E : -NZL2E;
    }
    __syncthreads();

    // ---- solve Q R = M (column sweep, 1 barrier/step); write P rows ----
    #pragma unroll 1
    for (int j = 0; j < 64; ++j) {
        const float fdi = dinv[j];
        if (c >= j) {
            const float* qc = qcol[j & 1];
            float qq[16];
            #pragma unroll
            for (int k = 0; k < 16; ++k) qq[k] = qc[i0 + k];
            if (c == j) {            // P[h][e=j][f] = Q[f][j]*sign(R[f][f])*NZL2E
                #pragma unroll
                for (int k = 0; k < 16; ++k)
                    P[h * 4096 + j * 64 + i0 + k] = qq[k] * fdi * sgnNZ[i0 + k];
            } else {
                const float f = Rs[j * 65 + c] * fdi;
                #pragma unroll
                for (int k = 0; k < 16; ++k) M[k] = fmaf(-qq[k], f, M[k]);
                if (c == j + 1) {
                    #pragma unroll
                    for (int k = 0; k < 16; ++k) qcol[(j + 1) & 1][i0 + k] = M[k];
                }
            }
        }
        __syncthreads();
    }
}

// -------- FAVOR+ map: 8 heads/block, 2-KB contiguous segments ---------------
__global__ __launch_bounds__(512, 4) void favor_kernel(const float* __restrict__ data,
                                                       const float* __restrict__ P,
                                                       float* __restrict__ out)
{
    // dbuf: 2 x (16 rows x 512 floats) = 64 KB
    __shared__ __attribute__((aligned(16))) float SMEM[2 * 8192];

    const int tid   = threadIdx.x;
    const int hg    = blockIdx.x & 1;               // head group: heads 8hg..8hg+7
    const int chunk = blockIdx.x >> 1;              // 0..511
    const size_t rowbase = (size_t)chunk * 128;     // 8 tiles x 16 rows

    const int lane = tid & 63;
    const int wv   = tid >> 6;                      // wave 0..7 -> head 8hg+wv
    const int ls   = lane & 15;                     // A-row / C-col
    const int lg   = lane >> 4;                     // k-group

    const float* db = data + (size_t)hg * 512;      // this block's 512-float chunk
    const int hd = hg * 8 + wv;                     // this wave's head

    // stage one 16-row x 512-float tile: per wave 4x gload16, each one
    // contiguous 1-KB half-row. Wave-uniform LDS dest; per-lane global source
    // XOR-pre-swizzled in the low 4 slot bits (slot = 16 B)  [rule 21].
#define STAGE(T, B) do {                                                           \
        const size_t rT_ = rowbase + (size_t)(T) * 16;                             \
        const int sl_ = (lane & ~15) | ((lane & 15) ^ 15);  /* dummy init */       \
        (void)sl_;                                                                 \
        _Pragma("unroll")                                                          \
        for (int i_ = 0; i_ < 4; ++i_) {                                           \
            const int hr_ = i_ * 8 + wv;            /* half-row 0..31 */           \
            const int r_  = hr_ >> 1;                                              \
            const int hf_ = hr_ & 1;                                               \
            const int sw_ = (lane & ~15) | ((lane & 15) ^ (r_ & 15));              \
            gload16(db + (rT_ + (size_t)r_) * 1024 + hf_ * 256 + sw_ * 4,          \
                    SMEM + (B) * 8192 + r_ * 512 + hf_ * 256);                     \
        }                                                                          \
    } while (0)

    STAGE(0, 0);

    // B fragments straight from global (L1/L2-cached; one head per wave).
    // B[k][col]: col = n*16 + ls, k = kh*32 + lg*8 + j.
    f16x8 bh[4][2], bl[4][2];
    #pragma unroll
    for (int n = 0; n < 4; ++n) {
        #pragma unroll
        for (int kh = 0; kh < 2; ++kh) {
            #pragma unroll
            for (int j = 0; j < 8; ++j) {
                const float pv = P[hd * 4096 + (kh * 32 + lg * 8 + j) * 64 + n * 16 + ls];
                const _Float16 hi = (_Float16)pv;
                bh[n][kh][j] = hi;
                bl[n][kh][j] = (_Float16)(pv - (float)hi);
            }
        }
    }
    __syncthreads();                 // tile 0 landed (implicit vmcnt(0) drain)

    const float SQS = 0.09016844005556021f;          // log2(e)/16
    #pragma unroll 1
    for (int t = 0; t < 8; ++t) {
        const int cb = t & 1;
        if (t < 7) STAGE(t + 1, cb ^ 1);             // in flight during compute

        float* strip = SMEM + cb * 8192;             // 16 rows x 512 floats
        const float* xr = strip + ls * 512 + wv * 64;   // A-row ls, head window

        // ---- A fragments (f16 hi/lo) + row sum-of-squares ----
        f16x8 ah[2], al[2];
        float sq = 0.f;
        #pragma unroll
        for (int kh = 0; kh < 2; ++kh) {
            const int s0 = (8 * kh + 2 * lg) ^ ls;       // swizzled 16B slots
            const int s1 = (8 * kh + 2 * lg + 1) ^ ls;
            const float4 va = *reinterpret_cast<const float4*>(xr + 4 * s0);
            const float4 vb = *reinterpret_cast<const float4*>(xr + 4 * s1);
            const float xs[8] = {va.x, va.y, va.z, va.w, vb.x, vb.y, vb.z, vb.w};
            #pragma unroll
            for (int j = 0; j < 8; ++j) {
                const float xv = xs[j];
                const _Float16 hi = (_Float16)xv;
                ah[kh][j] = hi;
                al[kh][j] = (_Float16)(xv - (float)hi);
                sq = fmaf(xv, xv, sq);
            }
        }
        sq += __shfl_xor(sq, 16);                        // complete 64-k sum
        sq += __shfl_xor(sq, 32);                        // (valid for row ls)

        // ---- 24 MFMAs: C = Xh*Bh + Xh*Bl + Xl*Bh ----
        f32x4 acc[4];
        #pragma unroll
        for (int n = 0; n < 4; ++n) {
            f32x4 a = {0.f, 0.f, 0.f, 0.f};
            #pragma unroll
            for (int kh = 0; kh < 2; ++kh) {
                a = __builtin_amdgcn_mfma_f32_16x16x32_f16(ah[kh], bh[n][kh], a, 0, 0, 0);
                a = __builtin_amdgcn_mfma_f32_16x16x32_f16(ah[kh], bl[n][kh], a, 0, 0, 0);
                a = __builtin_amdgcn_mfma_f32_16x16x32_f16(al[kh], bh[n][kh], a, 0, 0, 0);
            }
            acc[n] = a;
        }

        // ---- epilogue: exp2 + eps, transpose C through the wave's private
        //      column window of the current strip, then 4x store_dwordx4.
        //      Adjacent waves' windows merge into 2-KB contiguous segments. ----
        // write C[row][f] at window col (16n+ls)^(lg<<4)  (2-way banks, free)
        #pragma unroll
        for (int reg = 0; reg < 4; ++reg) {
            const int row_i = 4 * lg + reg;
            const float sqr = __shfl(sq, row_i) * SQS;   // from lane ls = row_i
            #pragma unroll
            for (int n = 0; n < 4; ++n)
                strip[row_i * 512 + wv * 64 + ((16 * n + ls) ^ (lg << 4))] =
                    EXP2F(acc[n][reg] - sqr) + 1e-6f;
        }
        // read back: lane(ls,lg), store s: row = 4s+lg, f0 = 4ls;
        // element (row,f) lives at window col f ^ ((row>>2)<<4) = f ^ (s<<4)
        const size_t rowT = rowbase + (size_t)t * 16;
        #pragma unroll
        for (int s = 0; s < 4; ++s) {
            const int row = 4 * s + lg;
            const float4 v = *reinterpret_cast<const float4*>(
                strip + row * 512 + wv * 64 + ((4 * ls) ^ (s << 4)));
            *reinterpret_cast<float4*>(
                out + (rowT + (size_t)row) * 1024 + (size_t)hd * 64 + 4 * ls) = v;
        }

        __syncthreads();   // drains vmcnt (next tile landed) + lgkm; buf swap safe
    }
#undef STAGE
}

extern "C" void kernel_launch(void* const* d_in, const int* in_sizes, int n_in,
                              void* d_out, int out_size, void* d_ws, size_t ws_size,
                              hipStream_t stream)
{
    const float* data = (const float*)d_in[0];   // (L,N,H,E) fp32
    const float* pm   = (const float*)d_in[1];   // (H,E,E)   fp32
    float* out = (float*)d_out;                  // (L,N,H,F) fp32
    float* P   = (float*)d_ws;                   // 16*64*64*4 = 256 KB scratch

    qr_kernel<<<16, 256, 0, stream>>>(pm, P);
    favor_kernel<<<1024, 512, 0, stream>>>(data, P, out);
}

// Round 14
// 210.217 us; speedup vs baseline: 1.0141x; 1.0141x over previous
//
#include <hip/hip_runtime.h>
#include <math.h>

// L=4096, N=16, H=16, E=64. rho = L*N = 65536 rows of 1024 floats (head h at +64h).
// out[rho][h][f] = exp2( x.Ps[h][:,f] - sq*SQS ) + 1e-6, Ps = proj*64^-.25*log2e.
// proj = q^T D, D = sign(diag(r)) of LAPACK-convention QR(pm[h]^T) (convention-
// dependent — must reproduce geqrf signs). Factor then Q = M R^-1.
// favor: f16 hi/lo split MFMA (C = Xh*Bh + Xh*Bl + Xl*Bh), residual ~2^-23.
// Round-14 ABLATION-BY-SUBSTITUTION: staging via registers (global_load_dwordx4
// -> VGPR -> ds_write_b128, T14 split) instead of global_load_lds. Identical
// address footprint/LDS layout/compute to r12. Tests whether the direct-to-LDS
// path caps the HBM stream at the ~3.4 TB/s plateau seen in r6-r13 (the m13
// 6.29 TB/s ceiling was measured through the VGPR path).

typedef _Float16 f16x8 __attribute__((ext_vector_type(8)));
typedef float    f32x4 __attribute__((ext_vector_type(4)));

#if __has_builtin(__builtin_amdgcn_exp2f)
#define EXP2F(x) __builtin_amdgcn_exp2f(x)
#else
#define EXP2F(x) exp2f(x)
#endif

// ---------------- per-head QR (fp32 Householder, LAPACK dlarfg signs) -------
__global__ __launch_bounds__(256) void qr_kernel(const float* __restrict__ pm,
                                                 float* __restrict__ P)
{
    __shared__ float colb[2][64];
    __shared__ float nrmb[2];
    __shared__ float Rs[64 * 65];
    __shared__ float qcol[2][64];
    __shared__ float dval[64];
    __shared__ float dinv[64];
    __shared__ float sgnNZ[64];

    const int tid = threadIdx.x;
    const int h   = blockIdx.x;
    const int c   = tid >> 2;       // column 0..63 (quad = 4 consecutive lanes)
    const int q   = tid & 3;        // row-quarter
    const int i0  = q * 16;

    float A[16], M[16];             // A[k] = M[i0+k][c] = pm[h][c][i0+k]
    {
        const float4* src = reinterpret_cast<const float4*>(pm + h * 4096 + c * 64 + i0);
        #pragma unroll
        for (int k4 = 0; k4 < 4; ++k4) {
            const float4 v = src[k4];
            A[4*k4+0] = M[4*k4+0] = v.x;
            A[4*k4+1] = M[4*k4+1] = v.y;
            A[4*k4+2] = M[4*k4+2] = v.z;
            A[4*k4+3] = M[4*k4+3] = v.w;
        }
    }
    if (c == 0) {                    // publish column 0 + its sub-norm
        #pragma unroll
        for (int k = 0; k < 16; ++k) colb[0][i0 + k] = A[k];
        float np = 0.f;
        #pragma unroll
        for (int k = 0; k < 16; ++k) if (i0 + k >= 1) np = fmaf(A[k], A[k], np);
        np += __shfl_xor(np, 1); np += __shfl_xor(np, 2);
        if (q == 0) nrmb[0] = np;
    }
    __syncthreads();

    // ---- factor: 64 Householder steps, 1 barrier each ----
    #pragma unroll 1
    for (int j = 0; j < 64; ++j) {
        const float* cbuf = colb[j & 1];
        const float alpha = cbuf[j];
        const float nrm2  = nrmb[j & 1];
        float beta, g;
        if (nrm2 == 0.f) { beta = alpha; g = 0.f; }          // H = I, tau = 0
        else {
            const float an = sqrtf(fmaf(alpha, alpha, nrm2));
            beta = (alpha >= 0.f) ? -an : an;                // -sign(alpha)*norm
            g    = 1.f / (beta * (beta - alpha));            // tau/(alpha-beta)^2
        }
        if (c >= j) {
            float cb[16];
            #pragma unroll
            for (int k = 0; k < 16; ++k) cb[k] = cbuf[i0 + k];
            float wp = 0.f, Ajc = 0.f;
            #pragma unroll
            for (int k = 0; k < 16; ++k) {
                const int i = i0 + k;
                wp  = fmaf((i > j) ? cb[k] : 0.f, A[k], wp); // v0 (i>j) part
                Ajc += (i == j) ? A[k] : 0.f;                // A[j][c]
            }
            wp  += __shfl_xor(wp, 1);  wp  += __shfl_xor(wp, 2);
            Ajc += __shfl_xor(Ajc, 1); Ajc += __shfl_xor(Ajc, 2);
            const float amb = alpha - beta;
            const float gw  = g * (wp + amb * Ajc);          // g * v0^T A[:,c]
            #pragma unroll
            for (int k = 0; k < 16; ++k) {
                const int i = i0 + k;
                const float v0 = (i > j) ? cb[k] : ((i == j) ? amb : 0.f);
                A[k] = fmaf(-gw, v0, A[k]);
            }
            if (c == j + 1) {        // publish next column into the OTHER buffer
                #pragma unroll
                for (int k = 0; k < 16; ++k) colb[(j + 1) & 1][i0 + k] = A[k];
                float np = 0.f;
                #pragma unroll
                for (int k = 0; k < 16; ++k) {
                    const int i = i0 + k;
                    np = fmaf((i > j + 1) ? A[k] : 0.f, A[k], np);
                }
                np += __shfl_xor(np, 1); np += __shfl_xor(np, 2);
                if (q == 0) nrmb[(j + 1) & 1] = np;
            }
        }
        __syncthreads();
    }

    // ---- R to LDS, diag inverses/signs, qcol prologue ----
    #pragma unroll
    for (int k = 0; k < 16; ++k) Rs[(i0 + k) * 65 + c] = A[k];
    {
        float dv = 0.f;
        #pragma unroll
        for (int k = 0; k < 16; ++k) dv += (i0 + k == c) ? A[k] : 0.f;
        dv += __shfl_xor(dv, 1); dv += __shfl_xor(dv, 2);
        if (q == 0) dval[c] = dv;
    }
    if (c == 0) {
        #pragma unroll
        for (int k = 0; k < 16; ++k) qcol[0][i0 + k] = M[k];
    }
    __syncthreads();
    if (tid < 64) {
        const float d = dval[tid];
        dinv[tid] = 1.f / d;
        const float NZL2E = 0.51012934f;     // 64^-0.25 * log2(e)
        sgnNZ[tid] = (d >= 0.f) ? NZL2E : -NZL2E;
    }
    __syncthreads();

    // ---- solve Q R = M (column sweep, 1 barrier/step); write P rows ----
    #pragma unroll 1
    for (int j = 0; j < 64; ++j) {
        const float fdi = dinv[j];
        if (c >= j) {
            const float* qc = qcol[j & 1];
            float qq[16];
            #pragma unroll
            for (int k = 0; k < 16; ++k) qq[k] = qc[i0 + k];
            if (c == j) {            // P[h][e=j][f] = Q[f][j]*sign(R[f][f])*NZL2E
                #pragma unroll
                for (int k = 0; k < 16; ++k)
                    P[h * 4096 + j * 64 + i0 + k] = qq[k] * fdi * sgnNZ[i0 + k];
            } else {
                const float f = Rs[j * 65 + c] * fdi;
                #pragma unroll
                for (int k = 0; k < 16; ++k) M[k] = fmaf(-qq[k], f, M[k]);
                if (c == j + 1) {
                    #pragma unroll
                    for (int k = 0; k < 16; ++k) qcol[(j + 1) & 1][i0 + k] = M[k];
                }
            }
        }
        __syncthreads();
    }
}

// -------- FAVOR+ map: f16-split MFMA, register-staged double-buffer ---------
__global__ __launch_bounds__(256, 3) void favor_kernel(const float* __restrict__ data,
                                                       const float* __restrict__ P,
                                                       float* __restrict__ out)
{
    __shared__ __attribute__((aligned(16))) float SMEM[2 * 4096];   // 32 KB dbuf

    const int tid   = threadIdx.x;
    const int h     = blockIdx.x & 15;
    const int chunk = blockIdx.x >> 4;              // 0..127
    const size_t rowbase = (size_t)chunk * 512;     // 8 tiles x 64 rows

    const int lane = tid & 63;
    const int wv   = tid >> 6;                      // wave owns rows 16wv..16wv+15
    const int ls   = lane & 15;                     // slot / A-row / C-col
    const int lg   = lane >> 4;                     // k-group

    const float* db = data + (size_t)h * 64;

    // block-cooperative staging task: task = tid + 256k -> row = task>>4 (0..63),
    // slot = task&15. Global read: 16 consecutive lanes cover one row's 256 B.
    const int srow  = tid >> 4;                     // rows srow, srow+16, ...
    const int sslot = tid & 15;

    // T14 split: issue loads early...
#define LOADREG(T, R) do {                                                         \
        const size_t rT_ = rowbase + (size_t)(T) * 64;                             \
        _Pragma("unroll")                                                          \
        for (int k_ = 0; k_ < 4; ++k_) {                                           \
            const int r_ = srow + 16 * k_;                                         \
            (R)[k_] = *reinterpret_cast<const float4*>(                            \
                db + (rT_ + (size_t)r_) * 1024 + sslot * 4);                       \
        }                                                                          \
    } while (0)

    // ...write to LDS late, with the read-side swizzle applied at the write:
    // row r, logical slot s -> phys slot s^(r&15)  (strip layout: r*64 floats)
#define WRITELDS(B, R) do {                                                        \
        float* buf_ = SMEM + (B) * 4096;                                           \
        _Pragma("unroll")                                                          \
        for (int k_ = 0; k_ < 4; ++k_) {                                           \
            const int r_ = srow + 16 * k_;                                         \
            *reinterpret_cast<float4*>(                                            \
                buf_ + r_ * 64 + ((sslot ^ (r_ & 15)) << 2)) = (R)[k_];            \
        }                                                                          \
    } while (0)

    float4 stg[4];
    LOADREG(0, stg);

    // B fragments straight from global (L1/L2-cached, shared by all blocks of
    // this head). B[k][col]: col = n*16 + ls, k = kh*32 + lg*8 + j.
    f16x8 bh[4][2], bl[4][2];
    #pragma unroll
    for (int n = 0; n < 4; ++n) {
        #pragma unroll
        for (int kh = 0; kh < 2; ++kh) {
            #pragma unroll
            for (int j = 0; j < 8; ++j) {
                const float pv = P[h * 4096 + (kh * 32 + lg * 8 + j) * 64 + n * 16 + ls];
                const _Float16 hi = (_Float16)pv;
                bh[n][kh][j] = hi;
                bl[n][kh][j] = (_Float16)(pv - (float)hi);
            }
        }
    }
    WRITELDS(0, stg);
    __syncthreads();                 // tile 0 in LDS, visible to all

    const float SQS = 0.09016844005556021f;          // log2(e)/16
    #pragma unroll 1
    for (int t = 0; t < 8; ++t) {
        const int cb = t & 1;
        if (t < 7) LOADREG(t + 1, stg);              // in flight during compute

        float* strip = SMEM + cb * 4096 + wv * 1024;    // wave-private 16x64
        const float* xr = strip + ls * 64;              // A-row ls

        // ---- A fragments (f16 hi/lo) + row sum-of-squares ----
        f16x8 ah[2], al[2];
        float sq = 0.f;
        #pragma unroll
        for (int kh = 0; kh < 2; ++kh) {
            const int s0 = (8 * kh + 2 * lg) ^ ls;       // swizzled 16B slots
            const int s1 = (8 * kh + 2 * lg + 1) ^ ls;
            const float4 va = *reinterpret_cast<const float4*>(xr + 4 * s0);
            const float4 vb = *reinterpret_cast<const float4*>(xr + 4 * s1);
            const float xs[8] = {va.x, va.y, va.z, va.w, vb.x, vb.y, vb.z, vb.w};
            #pragma unroll
            for (int j = 0; j < 8; ++j) {
                const float xv = xs[j];
                const _Float16 hi = (_Float16)xv;
                ah[kh][j] = hi;
                al[kh][j] = (_Float16)(xv - (float)hi);
                sq = fmaf(xv, xv, sq);
            }
        }
        sq += __shfl_xor(sq, 16);                        // complete 64-k sum
        sq += __shfl_xor(sq, 32);                        // (valid for row ls)

        // ---- 24 MFMAs: C = Xh*Bh + Xh*Bl + Xl*Bh ----
        f32x4 acc[4];
        #pragma unroll
        for (int n = 0; n < 4; ++n) {
            f32x4 a = {0.f, 0.f, 0.f, 0.f};
            #pragma unroll
            for (int kh = 0; kh < 2; ++kh) {
                a = __builtin_amdgcn_mfma_f32_16x16x32_f16(ah[kh], bh[n][kh], a, 0, 0, 0);
                a = __builtin_amdgcn_mfma_f32_16x16x32_f16(ah[kh], bl[n][kh], a, 0, 0, 0);
                a = __builtin_amdgcn_mfma_f32_16x16x32_f16(al[kh], bh[n][kh], a, 0, 0, 0);
            }
            acc[n] = a;
        }

        // ---- epilogue: exp2 + eps, transpose C through own (consumed) strip,
        //      then 4x global_store_dwordx4 (4 rows x 256 B segments) ----
        // write C[row][f] at strip[row*64 + ((16n+ls)^(lg<<4))]  (2-way banks)
        #pragma unroll
        for (int reg = 0; reg < 4; ++reg) {
            const int row_i = 4 * lg + reg;
            const float sqr = __shfl(sq, row_i) * SQS;   // from lane ls = row_i
            #pragma unroll
            for (int n = 0; n < 4; ++n)
                strip[row_i * 64 + ((16 * n + ls) ^ (lg << 4))] =
                    EXP2F(acc[n][reg] - sqr) + 1e-6f;
        }
        // read back: lane(ls,lg), store s: row = 4s+lg, f0 = 4ls;
        // element (row,f) lives at f ^ ((row>>2)<<4) = f ^ (s<<4)
        const size_t rowT = rowbase + (size_t)t * 64 + 16 * wv;
        #pragma unroll
        for (int s = 0; s < 4; ++s) {
            const int row = 4 * s + lg;
            const float4 v = *reinterpret_cast<const float4*>(
                strip + row * 64 + ((4 * ls) ^ (s << 4)));
            *reinterpret_cast<float4*>(
                out + (rowT + (size_t)row) * 1024 + (size_t)h * 64 + 4 * ls) = v;
        }

        if (t < 7) WRITELDS(cb ^ 1, stg);    // stage next tile into other buffer
        __syncthreads();                     // tile t+1 visible; strips reusable
    }
#undef LOADREG
#undef WRITELDS
}

extern "C" void kernel_launch(void* const* d_in, const int* in_sizes, int n_in,
                              void* d_out, int out_size, void* d_ws, size_t ws_size,
                              hipStream_t stream)
{
    const float* data = (const float*)d_in[0];   // (L,N,H,E) fp32
    const float* pm   = (const float*)d_in[1];   // (H,E,E)   fp32
    float* out = (float*)d_out;                  // (L,N,H,F) fp32
    float* P   = (float*)d_ws;                   // 16*64*64*4 = 256 KB scratch

    qr_kernel<<<16, 256, 0, stream>>>(pm, P);
    favor_kernel<<<2048, 256, 0, stream>>>(data, P, out);
}

// Round 15
// 186.129 us; speedup vs baseline: 1.1453x; 1.1294x over previous
//
#include <hip/hip_runtime.h>
#include <math.h>

// L=4096, N=16, H=16, E=64. rho = L*N = 65536 rows of 1024 floats (head h at +64h).
// out[rho][h][f] = exp2( x.Ps[h][:,f] - sq*SQS ) + 1e-6, Ps = proj*64^-.25*log2e.
// proj = q^T D, D = sign(diag(r)) of LAPACK-convention QR(pm[h]^T) (convention-
// dependent — must reproduce geqrf signs). Factor then Q = M R^-1.
// favor: f16 hi/lo split MFMA (C = Xh*Bh + Xh*Bl + Xl*Bh), residual ~2^-23.
// Round-15: ZERO barriers, zero shared staging. A-fragments loaded directly
// global->VGPR in MFMA lane order (lane(ls,lg): row ls, cols 8lg/32+8lg).
// r6-r14 all shared a barrier/wait-delimited tile-period structure and all
// plateaued at ~10us/period regardless of traffic (405-638 MB at constant
// time) => latency-serialized chain, not bandwidth. Here waves free-run.

typedef _Float16 f16x8 __attribute__((ext_vector_type(8)));
typedef float    f32x4 __attribute__((ext_vector_type(4)));

#if __has_builtin(__builtin_amdgcn_exp2f)
#define EXP2F(x) __builtin_amdgcn_exp2f(x)
#else
#define EXP2F(x) exp2f(x)
#endif

// ---------------- per-head QR (fp32 Householder, LAPACK dlarfg signs) -------
__global__ __launch_bounds__(256) void qr_kernel(const float* __restrict__ pm,
                                                 float* __restrict__ P)
{
    __shared__ float colb[2][64];
    __shared__ float nrmb[2];
    __shared__ float Rs[64 * 65];
    __shared__ float qcol[2][64];
    __shared__ float dval[64];
    __shared__ float dinv[64];
    __shared__ float sgnNZ[64];

    const int tid = threadIdx.x;
    const int h   = blockIdx.x;
    const int c   = tid >> 2;       // column 0..63 (quad = 4 consecutive lanes)
    const int q   = tid & 3;        // row-quarter
    const int i0  = q * 16;

    float A[16], M[16];             // A[k] = M[i0+k][c] = pm[h][c][i0+k]
    {
        const float4* src = reinterpret_cast<const float4*>(pm + h * 4096 + c * 64 + i0);
        #pragma unroll
        for (int k4 = 0; k4 < 4; ++k4) {
            const float4 v = src[k4];
            A[4*k4+0] = M[4*k4+0] = v.x;
            A[4*k4+1] = M[4*k4+1] = v.y;
            A[4*k4+2] = M[4*k4+2] = v.z;
            A[4*k4+3] = M[4*k4+3] = v.w;
        }
    }
    if (c == 0) {                    // publish column 0 + its sub-norm
        #pragma unroll
        for (int k = 0; k < 16; ++k) colb[0][i0 + k] = A[k];
        float np = 0.f;
        #pragma unroll
        for (int k = 0; k < 16; ++k) if (i0 + k >= 1) np = fmaf(A[k], A[k], np);
        np += __shfl_xor(np, 1); np += __shfl_xor(np, 2);
        if (q == 0) nrmb[0] = np;
    }
    __syncthreads();

    // ---- factor: 64 Householder steps, 1 barrier each ----
    #pragma unroll 1
    for (int j = 0; j < 64; ++j) {
        const float* cbuf = colb[j & 1];
        const float alpha = cbuf[j];
        const float nrm2  = nrmb[j & 1];
        float beta, g;
        if (nrm2 == 0.f) { beta = alpha; g = 0.f; }          // H = I, tau = 0
        else {
            const float an = sqrtf(fmaf(alpha, alpha, nrm2));
            beta = (alpha >= 0.f) ? -an : an;                // -sign(alpha)*norm
            g    = 1.f / (beta * (beta - alpha));            // tau/(alpha-beta)^2
        }
        if (c >= j) {
            float cb[16];
            #pragma unroll
            for (int k = 0; k < 16; ++k) cb[k] = cbuf[i0 + k];
            float wp = 0.f, Ajc = 0.f;
            #pragma unroll
            for (int k = 0; k < 16; ++k) {
                const int i = i0 + k;
                wp  = fmaf((i > j) ? cb[k] : 0.f, A[k], wp); // v0 (i>j) part
                Ajc += (i == j) ? A[k] : 0.f;                // A[j][c]
            }
            wp  += __shfl_xor(wp, 1);  wp  += __shfl_xor(wp, 2);
            Ajc += __shfl_xor(Ajc, 1); Ajc += __shfl_xor(Ajc, 2);
            const float amb = alpha - beta;
            const float gw  = g * (wp + amb * Ajc);          // g * v0^T A[:,c]
            #pragma unroll
            for (int k = 0; k < 16; ++k) {
                const int i = i0 + k;
                const float v0 = (i > j) ? cb[k] : ((i == j) ? amb : 0.f);
                A[k] = fmaf(-gw, v0, A[k]);
            }
            if (c == j + 1) {        // publish next column into the OTHER buffer
                #pragma unroll
                for (int k = 0; k < 16; ++k) colb[(j + 1) & 1][i0 + k] = A[k];
                float np = 0.f;
                #pragma unroll
                for (int k = 0; k < 16; ++k) {
                    const int i = i0 + k;
                    np = fmaf((i > j + 1) ? A[k] : 0.f, A[k], np);
                }
                np += __shfl_xor(np, 1); np += __shfl_xor(np, 2);
                if (q == 0) nrmb[(j + 1) & 1] = np;
            }
        }
        __syncthreads();
    }

    // ---- R to LDS, diag inverses/signs, qcol prologue ----
    #pragma unroll
    for (int k = 0; k < 16; ++k) Rs[(i0 + k) * 65 + c] = A[k];
    {
        float dv = 0.f;
        #pragma unroll
        for (int k = 0; k < 16; ++k) dv += (i0 + k == c) ? A[k] : 0.f;
        dv += __shfl_xor(dv, 1); dv += __shfl_xor(dv, 2);
        if (q == 0) dval[c] = dv;
    }
    if (c == 0) {
        #pragma unroll
        for (int k = 0; k < 16; ++k) qcol[0][i0 + k] = M[k];
    }
    __syncthreads();
    if (tid < 64) {
        const float d = dval[tid];
        dinv[tid] = 1.f / d;
        const float NZL2E = 0.51012934f;     // 64^-0.25 * log2(e)
        sgnNZ[tid] = (d >= 0.f) ? NZL2E : -NZL2E;
    }
    __syncthreads();

    // ---- solve Q R = M (column sweep, 1 barrier/step); write P rows ----
    #pragma unroll 1
    for (int j = 0; j < 64; ++j) {
        const float fdi = dinv[j];
        if (c >= j) {
            const float* qc = qcol[j & 1];
            float qq[16];
            #pragma unroll
            for (int k = 0; k < 16; ++k) qq[k] = qc[i0 + k];
            if (c == j) {            // P[h][e=j][f] = Q[f][j]*sign(R[f][f])*NZL2E
                #pragma unroll
                for (int k = 0; k < 16; ++k)
                    P[h * 4096 + j * 64 + i0 + k] = qq[k] * fdi * sgnNZ[i0 + k];
            } else {
                const float f = Rs[j * 65 + c] * fdi;
                #pragma unroll
                for (int k = 0; k < 16; ++k) M[k] = fmaf(-qq[k], f, M[k]);
                if (c == j + 1) {
                    #pragma unroll
                    for (int k = 0; k < 16; ++k) qcol[(j + 1) & 1][i0 + k] = M[k];
                }
            }
        }
        __syncthreads();
    }
}

// -------- FAVOR+ map: direct global->VGPR fragments, zero barriers ----------
__global__ __launch_bounds__(256, 3) void favor_kernel(const float* __restrict__ data,
                                                       const float* __restrict__ P,
                                                       float* __restrict__ out)
{
    __shared__ __attribute__((aligned(16))) float SMEM[4096];   // 4 KB/wave scratch

    const int tid   = threadIdx.x;
    const int h     = blockIdx.x & 15;
    const int chunk = blockIdx.x >> 4;              // 0..127
    const size_t rowbase = (size_t)chunk * 512;     // 8 tiles x 64 rows

    const int lane = tid & 63;
    const int wv   = tid >> 6;                      // wave owns rows 16wv..16wv+15
    const int ls   = lane & 15;                     // A-row / C-col
    const int lg   = lane >> 4;                     // k-group

    const float* db = data + (size_t)h * 64;
    const int c0 = lg * 8;                          // lane's k-slice base col

    // A-fragment loads in MFMA lane order: lane (ls,lg) reads row ls,
    // cols c0..c0+7 (kh=0) and 32+c0..32+c0+7 (kh=1): 4x dwordx4.
#define LOADX(T, X) do {                                                           \
        const float* rp_ = db + (rowbase + (size_t)(T) * 64 + 16 * wv + ls) * 1024;\
        (X)[0] = *reinterpret_cast<const float4*>(rp_ + c0);                       \
        (X)[1] = *reinterpret_cast<const float4*>(rp_ + c0 + 4);                   \
        (X)[2] = *reinterpret_cast<const float4*>(rp_ + c0 + 32);                  \
        (X)[3] = *reinterpret_cast<const float4*>(rp_ + c0 + 36);                  \
    } while (0)

    float4 xv[4];
    LOADX(0, xv);                                   // prologue

    // B fragments straight from global (L1/L2-cached, shared by all blocks of
    // this head). B[k][col]: col = n*16 + ls, k = kh*32 + lg*8 + j.
    f16x8 bh[4][2], bl[4][2];
    #pragma unroll
    for (int n = 0; n < 4; ++n) {
        #pragma unroll
        for (int kh = 0; kh < 2; ++kh) {
            #pragma unroll
            for (int j = 0; j < 8; ++j) {
                const float pv = P[h * 4096 + (kh * 32 + lg * 8 + j) * 64 + n * 16 + ls];
                const _Float16 hi = (_Float16)pv;
                bh[n][kh][j] = hi;
                bl[n][kh][j] = (_Float16)(pv - (float)hi);
            }
        }
    }

    float* strip = SMEM + wv * 1024;                // wave-private 16x64 scratch
    const float SQS = 0.09016844005556021f;         // log2(e)/16

    #pragma unroll 1
    for (int t = 0; t < 8; ++t) {
        // ---- convert current tile regs -> A fragments + sq partial ----
        f16x8 ah[2], al[2];
        float sq = 0.f;
        #pragma unroll
        for (int kh = 0; kh < 2; ++kh) {
            const float xs[8] = {xv[2*kh].x, xv[2*kh].y, xv[2*kh].z, xv[2*kh].w,
                                 xv[2*kh+1].x, xv[2*kh+1].y, xv[2*kh+1].z, xv[2*kh+1].w};
            #pragma unroll
            for (int j = 0; j < 8; ++j) {
                const float x = xs[j];
                const _Float16 hi = (_Float16)x;
                ah[kh][j] = hi;
                al[kh][j] = (_Float16)(x - (float)hi);
                sq = fmaf(x, x, sq);
            }
        }
        // ---- issue next tile's loads (before MFMA/stores: FIFO-decoupled) ----
        if (t < 7) LOADX(t + 1, xv);

        sq += __shfl_xor(sq, 16);                   // sum over lg groups
        sq += __shfl_xor(sq, 32);                   // (valid for row ls)

        // ---- 24 MFMAs: C = Xh*Bh + Xh*Bl + Xl*Bh ----
        f32x4 acc[4];
        #pragma unroll
        for (int n = 0; n < 4; ++n) {
            f32x4 a = {0.f, 0.f, 0.f, 0.f};
            #pragma unroll
            for (int kh = 0; kh < 2; ++kh) {
                a = __builtin_amdgcn_mfma_f32_16x16x32_f16(ah[kh], bh[n][kh], a, 0, 0, 0);
                a = __builtin_amdgcn_mfma_f32_16x16x32_f16(ah[kh], bl[n][kh], a, 0, 0, 0);
                a = __builtin_amdgcn_mfma_f32_16x16x32_f16(al[kh], bh[n][kh], a, 0, 0, 0);
            }
            acc[n] = a;
        }

        // ---- epilogue: exp2+eps, transpose C through wave-private LDS strip
        //      (lgkmcnt-only sync; no barrier), then 4x global_store_dwordx4 ----
        // write C[row][f] at strip[row*64 + ((16n+ls)^(lg<<4))]  (2-way banks)
        #pragma unroll
        for (int reg = 0; reg < 4; ++reg) {
            const int row_i = 4 * lg + reg;
            const float sqr = __shfl(sq, row_i) * SQS;   // from lane ls = row_i
            #pragma unroll
            for (int n = 0; n < 4; ++n)
                strip[row_i * 64 + ((16 * n + ls) ^ (lg << 4))] =
                    EXP2F(acc[n][reg] - sqr) + 1e-6f;
        }
        asm volatile("s_waitcnt lgkmcnt(0)" ::: "memory");   // writes visible
        // read back: lane(ls,lg), store s: row = 4s+lg, f0 = 4ls;
        // element (row,f) lives at f ^ ((row>>2)<<4) = f ^ (s<<4)
        const size_t rowT = rowbase + (size_t)t * 64 + 16 * wv;
        #pragma unroll
        for (int s = 0; s < 4; ++s) {
            const int row = 4 * s + lg;
            const float4 v = *reinterpret_cast<const float4*>(
                strip + row * 64 + ((4 * ls) ^ (s << 4)));
            *reinterpret_cast<float4*>(
                out + (rowT + (size_t)row) * 1024 + (size_t)h * 64 + 4 * ls) = v;
        }
        asm volatile("s_waitcnt lgkmcnt(0)" ::: "memory");   // reads done before
                                                             // next iter rewrites
    }
#undef LOADX
}

extern "C" void kernel_launch(void* const* d_in, const int* in_sizes, int n_in,
                              void* d_out, int out_size, void* d_ws, size_t ws_size,
                              hipStream_t stream)
{
    const float* data = (const float*)d_in[0];   // (L,N,H,E) fp32
    const float* pm   = (const float*)d_in[1];   // (H,E,E)   fp32
    float* out = (float*)d_out;                  // (L,N,H,F) fp32
    float* P   = (float*)d_ws;                   // 16*64*64*4 = 256 KB scratch

    qr_kernel<<<16, 256, 0, stream>>>(pm, P);
    favor_kernel<<<2048, 256, 0, stream>>>(data, P, out);
}

// Round 16
// 179.277 us; speedup vs baseline: 1.1891x; 1.0382x over previous
//
#include <hip/hip_runtime.h>
#include <math.h>

// L=4096, N=16, H=16, E=64. rho = L*N = 65536 rows of 1024 floats (head h at +64h).
// out[rho][h][f] = exp2( x.Ps[h][:,f] - sq*SQS ) + 1e-6, Ps = proj*64^-.25*log2e.
// proj = q^T D, D = sign(diag(r)) of LAPACK-convention QR(pm[h]^T) (convention-
// dependent — must reproduce geqrf signs). Factor then Q = M R^-1.
// favor: f16 hi/lo split MFMA (C = Xh*Bh + Xh*Bl + Xl*Bh), residual ~2^-23.
// Round-16: r15 + head-derangement h=(blockIdx+chunk)&15. With h=blockIdx&15,
// XCD k (= blockIdx%8) ran ONLY heads {k,k+8} -> address bits [8:11] fixed per
// XCD -> L2-bank/fabric concentration capping BW at ~3.6 TB/s in ALL of
// r6-r15. The derangement spreads all 16 head-offsets across every XCD.

typedef _Float16 f16x8 __attribute__((ext_vector_type(8)));
typedef float    f32x4 __attribute__((ext_vector_type(4)));

#if __has_builtin(__builtin_amdgcn_exp2f)
#define EXP2F(x) __builtin_amdgcn_exp2f(x)
#else
#define EXP2F(x) exp2f(x)
#endif

// ---------------- per-head QR (fp32 Householder, LAPACK dlarfg signs) -------
__global__ __launch_bounds__(256) void qr_kernel(const float* __restrict__ pm,
                                                 float* __restrict__ P)
{
    __shared__ float colb[2][64];
    __shared__ float nrmb[2];
    __shared__ float Rs[64 * 65];
    __shared__ float qcol[2][64];
    __shared__ float dval[64];
    __shared__ float dinv[64];
    __shared__ float sgnNZ[64];

    const int tid = threadIdx.x;
    const int h   = blockIdx.x;
    const int c   = tid >> 2;       // column 0..63 (quad = 4 consecutive lanes)
    const int q   = tid & 3;        // row-quarter
    const int i0  = q * 16;

    float A[16], M[16];             // A[k] = M[i0+k][c] = pm[h][c][i0+k]
    {
        const float4* src = reinterpret_cast<const float4*>(pm + h * 4096 + c * 64 + i0);
        #pragma unroll
        for (int k4 = 0; k4 < 4; ++k4) {
            const float4 v = src[k4];
            A[4*k4+0] = M[4*k4+0] = v.x;
            A[4*k4+1] = M[4*k4+1] = v.y;
            A[4*k4+2] = M[4*k4+2] = v.z;
            A[4*k4+3] = M[4*k4+3] = v.w;
        }
    }
    if (c == 0) {                    // publish column 0 + its sub-norm
        #pragma unroll
        for (int k = 0; k < 16; ++k) colb[0][i0 + k] = A[k];
        float np = 0.f;
        #pragma unroll
        for (int k = 0; k < 16; ++k) if (i0 + k >= 1) np = fmaf(A[k], A[k], np);
        np += __shfl_xor(np, 1); np += __shfl_xor(np, 2);
        if (q == 0) nrmb[0] = np;
    }
    __syncthreads();

    // ---- factor: 64 Householder steps, 1 barrier each ----
    #pragma unroll 1
    for (int j = 0; j < 64; ++j) {
        const float* cbuf = colb[j & 1];
        const float alpha = cbuf[j];
        const float nrm2  = nrmb[j & 1];
        float beta, g;
        if (nrm2 == 0.f) { beta = alpha; g = 0.f; }          // H = I, tau = 0
        else {
            const float an = sqrtf(fmaf(alpha, alpha, nrm2));
            beta = (alpha >= 0.f) ? -an : an;                // -sign(alpha)*norm
            g    = 1.f / (beta * (beta - alpha));            // tau/(alpha-beta)^2
        }
        if (c >= j) {
            float cb[16];
            #pragma unroll
            for (int k = 0; k < 16; ++k) cb[k] = cbuf[i0 + k];
            float wp = 0.f, Ajc = 0.f;
            #pragma unroll
            for (int k = 0; k < 16; ++k) {
                const int i = i0 + k;
                wp  = fmaf((i > j) ? cb[k] : 0.f, A[k], wp); // v0 (i>j) part
                Ajc += (i == j) ? A[k] : 0.f;                // A[j][c]
            }
            wp  += __shfl_xor(wp, 1);  wp  += __shfl_xor(wp, 2);
            Ajc += __shfl_xor(Ajc, 1); Ajc += __shfl_xor(Ajc, 2);
            const float amb = alpha - beta;
            const float gw  = g * (wp + amb * Ajc);          // g * v0^T A[:,c]
            #pragma unroll
            for (int k = 0; k < 16; ++k) {
                const int i = i0 + k;
                const float v0 = (i > j) ? cb[k] : ((i == j) ? amb : 0.f);
                A[k] = fmaf(-gw, v0, A[k]);
            }
            if (c == j + 1) {        // publish next column into the OTHER buffer
                #pragma unroll
                for (int k = 0; k < 16; ++k) colb[(j + 1) & 1][i0 + k] = A[k];
                float np = 0.f;
                #pragma unroll
                for (int k = 0; k < 16; ++k) {
                    const int i = i0 + k;
                    np = fmaf((i > j + 1) ? A[k] : 0.f, A[k], np);
                }
                np += __shfl_xor(np, 1); np += __shfl_xor(np, 2);
                if (q == 0) nrmb[(j + 1) & 1] = np;
            }
        }
        __syncthreads();
    }

    // ---- R to LDS, diag inverses/signs, qcol prologue ----
    #pragma unroll
    for (int k = 0; k < 16; ++k) Rs[(i0 + k) * 65 + c] = A[k];
    {
        float dv = 0.f;
        #pragma unroll
        for (int k = 0; k < 16; ++k) dv += (i0 + k == c) ? A[k] : 0.f;
        dv += __shfl_xor(dv, 1); dv += __shfl_xor(dv, 2);
        if (q == 0) dval[c] = dv;
    }
    if (c == 0) {
        #pragma unroll
        for (int k = 0; k < 16; ++k) qcol[0][i0 + k] = M[k];
    }
    __syncthreads();
    if (tid < 64) {
        const float d = dval[tid];
        dinv[tid] = 1.f / d;
        const float NZL2E = 0.51012934f;     // 64^-0.25 * log2(e)
        sgnNZ[tid] = (d >= 0.f) ? NZL2E : -NZL2E;
    }
    __syncthreads();

    // ---- solve Q R = M (column sweep, 1 barrier/step); write P rows ----
    #pragma unroll 1
    for (int j = 0; j < 64; ++j) {
        const float fdi = dinv[j];
        if (c >= j) {
            const float* qc = qcol[j & 1];
            float qq[16];
            #pragma unroll
            for (int k = 0; k < 16; ++k) qq[k] = qc[i0 + k];
            if (c == j) {            // P[h][e=j][f] = Q[f][j]*sign(R[f][f])*NZL2E
                #pragma unroll
                for (int k = 0; k < 16; ++k)
                    P[h * 4096 + j * 64 + i0 + k] = qq[k] * fdi * sgnNZ[i0 + k];
            } else {
                const float f = Rs[j * 65 + c] * fdi;
                #pragma unroll
                for (int k = 0; k < 16; ++k) M[k] = fmaf(-qq[k], f, M[k]);
                if (c == j + 1) {
                    #pragma unroll
                    for (int k = 0; k < 16; ++k) qcol[(j + 1) & 1][i0 + k] = M[k];
                }
            }
        }
        __syncthreads();
    }
}

// -------- FAVOR+ map: direct global->VGPR fragments, zero barriers ----------
__global__ __launch_bounds__(256, 3) void favor_kernel(const float* __restrict__ data,
                                                       const float* __restrict__ P,
                                                       float* __restrict__ out)
{
    __shared__ __attribute__((aligned(16))) float SMEM[4096];   // 4 KB/wave scratch

    const int tid   = threadIdx.x;
    const int chunk = blockIdx.x >> 4;              // 0..127
    const int h     = (blockIdx.x + chunk) & 15;    // head-derangement: every
                                                    // XCD sees all 16 offsets
    const size_t rowbase = (size_t)chunk * 512;     // 8 tiles x 64 rows

    const int lane = tid & 63;
    const int wv   = tid >> 6;                      // wave owns rows 16wv..16wv+15
    const int ls   = lane & 15;                     // A-row / C-col
    const int lg   = lane >> 4;                     // k-group

    const float* db = data + (size_t)h * 64;
    const int c0 = lg * 8;                          // lane's k-slice base col

    // A-fragment loads in MFMA lane order: lane (ls,lg) reads row ls,
    // cols c0..c0+7 (kh=0) and 32+c0..32+c0+7 (kh=1): 4x dwordx4.
#define LOADX(T, X) do {                                                           \
        const float* rp_ = db + (rowbase + (size_t)(T) * 64 + 16 * wv + ls) * 1024;\
        (X)[0] = *reinterpret_cast<const float4*>(rp_ + c0);                       \
        (X)[1] = *reinterpret_cast<const float4*>(rp_ + c0 + 4);                   \
        (X)[2] = *reinterpret_cast<const float4*>(rp_ + c0 + 32);                  \
        (X)[3] = *reinterpret_cast<const float4*>(rp_ + c0 + 36);                  \
    } while (0)

    float4 xv[4];
    LOADX(0, xv);                                   // prologue

    // B fragments straight from global (L1/L2-cached, shared by all blocks of
    // this head). B[k][col]: col = n*16 + ls, k = kh*32 + lg*8 + j.
    f16x8 bh[4][2], bl[4][2];
    #pragma unroll
    for (int n = 0; n < 4; ++n) {
        #pragma unroll
        for (int kh = 0; kh < 2; ++kh) {
            #pragma unroll
            for (int j = 0; j < 8; ++j) {
                const float pv = P[h * 4096 + (kh * 32 + lg * 8 + j) * 64 + n * 16 + ls];
                const _Float16 hi = (_Float16)pv;
                bh[n][kh][j] = hi;
                bl[n][kh][j] = (_Float16)(pv - (float)hi);
            }
        }
    }

    float* strip = SMEM + wv * 1024;                // wave-private 16x64 scratch
    const float SQS = 0.09016844005556021f;         // log2(e)/16

    #pragma unroll 1
    for (int t = 0; t < 8; ++t) {
        // ---- convert current tile regs -> A fragments + sq partial ----
        f16x8 ah[2], al[2];
        float sq = 0.f;
        #pragma unroll
        for (int kh = 0; kh < 2; ++kh) {
            const float xs[8] = {xv[2*kh].x, xv[2*kh].y, xv[2*kh].z, xv[2*kh].w,
                                 xv[2*kh+1].x, xv[2*kh+1].y, xv[2*kh+1].z, xv[2*kh+1].w};
            #pragma unroll
            for (int j = 0; j < 8; ++j) {
                const float x = xs[j];
                const _Float16 hi = (_Float16)x;
                ah[kh][j] = hi;
                al[kh][j] = (_Float16)(x - (float)hi);
                sq = fmaf(x, x, sq);
            }
        }
        // ---- issue next tile's loads (before MFMA/stores: FIFO-decoupled) ----
        if (t < 7) LOADX(t + 1, xv);

        sq += __shfl_xor(sq, 16);                   // sum over lg groups
        sq += __shfl_xor(sq, 32);                   // (valid for row ls)

        // ---- 24 MFMAs: C = Xh*Bh + Xh*Bl + Xl*Bh ----
        f32x4 acc[4];
        #pragma unroll
        for (int n = 0; n < 4; ++n) {
            f32x4 a = {0.f, 0.f, 0.f, 0.f};
            #pragma unroll
            for (int kh = 0; kh < 2; ++kh) {
                a = __builtin_amdgcn_mfma_f32_16x16x32_f16(ah[kh], bh[n][kh], a, 0, 0, 0);
                a = __builtin_amdgcn_mfma_f32_16x16x32_f16(ah[kh], bl[n][kh], a, 0, 0, 0);
                a = __builtin_amdgcn_mfma_f32_16x16x32_f16(al[kh], bh[n][kh], a, 0, 0, 0);
            }
            acc[n] = a;
        }

        // ---- epilogue: exp2+eps, transpose C through wave-private LDS strip
        //      (lgkmcnt-only sync; no barrier), then 4x global_store_dwordx4 ----
        // write C[row][f] at strip[row*64 + ((16n+ls)^(lg<<4))]  (2-way banks)
        #pragma unroll
        for (int reg = 0; reg < 4; ++reg) {
            const int row_i = 4 * lg + reg;
            const float sqr = __shfl(sq, row_i) * SQS;   // from lane ls = row_i
            #pragma unroll
            for (int n = 0; n < 4; ++n)
                strip[row_i * 64 + ((16 * n + ls) ^ (lg << 4))] =
                    EXP2F(acc[n][reg] - sqr) + 1e-6f;
        }
        asm volatile("s_waitcnt lgkmcnt(0)" ::: "memory");   // writes visible
        // read back: lane(ls,lg), store s: row = 4s+lg, f0 = 4ls;
        // element (row,f) lives at f ^ ((row>>2)<<4) = f ^ (s<<4)
        const size_t rowT = rowbase + (size_t)t * 64 + 16 * wv;
        #pragma unroll
        for (int s = 0; s < 4; ++s) {
            const int row = 4 * s + lg;
            const float4 v = *reinterpret_cast<const float4*>(
                strip + row * 64 + ((4 * ls) ^ (s << 4)));
            *reinterpret_cast<float4*>(
                out + (rowT + (size_t)row) * 1024 + (size_t)h * 64 + 4 * ls) = v;
        }
        asm volatile("s_waitcnt lgkmcnt(0)" ::: "memory");   // reads done before
                                                             // next iter rewrites
    }
#undef LOADX
}

extern "C" void kernel_launch(void* const* d_in, const int* in_sizes, int n_in,
                              void* d_out, int out_size, void* d_ws, size_t ws_size,
                              hipStream_t stream)
{
    const float* data = (const float*)d_in[0];   // (L,N,H,E) fp32
    const float* pm   = (const float*)d_in[1];   // (H,E,E)   fp32
    float* out = (float*)d_out;                  // (L,N,H,F) fp32
    float* P   = (float*)d_ws;                   // 16*64*64*4 = 256 KB scratch

    qr_kernel<<<16, 256, 0, stream>>>(pm, P);
    favor_kernel<<<2048, 256, 0, stream>>>(data, P, out);
}

// Round 18
// 149.290 us; speedup vs baseline: 1.4279x; 1.2009x over previous
//
#include <hip/hip_runtime.h>
#include <math.h>

// L=4096, N=16, H=16, E=64. rho = L*N = 65536 rows of 1024 floats (head h at +64h).
// out[rho][h][f] = exp2( x.Ps[h][:,f] - sq*SQS ) + 1e-6, Ps = proj*64^-.25*log2e.
// proj = q^T D, D = sign(diag(r)) of LAPACK-convention QR(pm[h]^T) (convention-
// dependent — must reproduce geqrf signs). Factor then Q = M R^-1.
// favor: f16 hi/lo split MFMA (C = Xh*Bh + Xh*Bl + Xl*Bh), residual ~2^-23.
// Round-18 = round-17 with the compile fix: nontemporal store takes a clang
// ext_vector_type pointer (HIP float4 is a class type the builtin rejects).
// (a) qr solve -> row-parallel forward substitution on wave 0, zero barriers;
// (b) favor out-stores nontemporal (protect 268-MB input's L3 residency).

typedef _Float16 f16x8 __attribute__((ext_vector_type(8)));
typedef float    f32x4 __attribute__((ext_vector_type(4)));

#if __has_builtin(__builtin_amdgcn_exp2f)
#define EXP2F(x) __builtin_amdgcn_exp2f(x)
#else
#define EXP2F(x) exp2f(x)
#endif

// ---------------- per-head QR (fp32 Householder, LAPACK dlarfg signs) -------
__global__ __launch_bounds__(256) void qr_kernel(const float* __restrict__ pm,
                                                 float* __restrict__ P)
{
    __shared__ float colb[2][64];
    __shared__ float nrmb[2];
    __shared__ float Rs[64 * 65];
    __shared__ float dval[64];
    __shared__ float dinv[64];
    __shared__ float sgnNZ[64];

    const int tid = threadIdx.x;
    const int h   = blockIdx.x;
    const int c   = tid >> 2;       // column 0..63 (quad = 4 consecutive lanes)
    const int q   = tid & 3;        // row-quarter
    const int i0  = q * 16;

    float A[16];                    // A[k] = M[i0+k][c] = pm[h][c][i0+k]
    {
        const float4* src = reinterpret_cast<const float4*>(pm + h * 4096 + c * 64 + i0);
        #pragma unroll
        for (int k4 = 0; k4 < 4; ++k4) {
            const float4 v = src[k4];
            A[4*k4+0] = v.x; A[4*k4+1] = v.y;
            A[4*k4+2] = v.z; A[4*k4+3] = v.w;
        }
    }
    if (c == 0) {                    // publish column 0 + its sub-norm
        #pragma unroll
        for (int k = 0; k < 16; ++k) colb[0][i0 + k] = A[k];
        float np = 0.f;
        #pragma unroll
        for (int k = 0; k < 16; ++k) if (i0 + k >= 1) np = fmaf(A[k], A[k], np);
        np += __shfl_xor(np, 1); np += __shfl_xor(np, 2);
        if (q == 0) nrmb[0] = np;
    }
    __syncthreads();

    // ---- factor: 64 Householder steps, 1 barrier each ----
    #pragma unroll 1
    for (int j = 0; j < 64; ++j) {
        const float* cbuf = colb[j & 1];
        const float alpha = cbuf[j];
        const float nrm2  = nrmb[j & 1];
        float beta, g;
        if (nrm2 == 0.f) { beta = alpha; g = 0.f; }          // H = I, tau = 0
        else {
            const float an = sqrtf(fmaf(alpha, alpha, nrm2));
            beta = (alpha >= 0.f) ? -an : an;                // -sign(alpha)*norm
            g    = 1.f / (beta * (beta - alpha));            // tau/(alpha-beta)^2
        }
        if (c >= j) {
            float cb[16];
            #pragma unroll
            for (int k = 0; k < 16; ++k) cb[k] = cbuf[i0 + k];
            float wp = 0.f, Ajc = 0.f;
            #pragma unroll
            for (int k = 0; k < 16; ++k) {
                const int i = i0 + k;
                wp  = fmaf((i > j) ? cb[k] : 0.f, A[k], wp); // v0 (i>j) part
                Ajc += (i == j) ? A[k] : 0.f;                // A[j][c]
            }
            wp  += __shfl_xor(wp, 1);  wp  += __shfl_xor(wp, 2);
            Ajc += __shfl_xor(Ajc, 1); Ajc += __shfl_xor(Ajc, 2);
            const float amb = alpha - beta;
            const float gw  = g * (wp + amb * Ajc);          // g * v0^T A[:,c]
            #pragma unroll
            for (int k = 0; k < 16; ++k) {
                const int i = i0 + k;
                const float v0 = (i > j) ? cb[k] : ((i == j) ? amb : 0.f);
                A[k] = fmaf(-gw, v0, A[k]);
            }
            if (c == j + 1) {        // publish next column into the OTHER buffer
                #pragma unroll
                for (int k = 0; k < 16; ++k) colb[(j + 1) & 1][i0 + k] = A[k];
                float np = 0.f;
                #pragma unroll
                for (int k = 0; k < 16; ++k) {
                    const int i = i0 + k;
                    np = fmaf((i > j + 1) ? A[k] : 0.f, A[k], np);
                }
                np += __shfl_xor(np, 1); np += __shfl_xor(np, 2);
                if (q == 0) nrmb[(j + 1) & 1] = np;
            }
        }
        __syncthreads();
    }

    // ---- R to LDS, diag inverses/signs ----
    #pragma unroll
    for (int k = 0; k < 16; ++k) Rs[(i0 + k) * 65 + c] = A[k];
    {
        float dv = 0.f;
        #pragma unroll
        for (int k = 0; k < 16; ++k) dv += (i0 + k == c) ? A[k] : 0.f;
        dv += __shfl_xor(dv, 1); dv += __shfl_xor(dv, 2);
        if (q == 0) dval[c] = dv;
    }
    __syncthreads();
    if (tid < 64) {
        const float d = dval[tid];
        dinv[tid] = 1.f / d;
        const float NZL2E = 0.51012934f;     // 64^-0.25 * log2(e)
        sgnNZ[tid] = (d >= 0.f) ? NZL2E : -NZL2E;
    }
    __syncthreads();

    // ---- solve Q R = M: row-parallel forward substitution, wave 0 only,
    //      ZERO barriers. Lane i owns row i: q_i[j] = (M[i][j] - sum_{k<j}
    //      q_i[k] R[k][j]) / R[j][j]. Fully unrolled -> all-static indexing.
    if (tid < 64) {
        const int i = tid;
        float r[64];
        #pragma unroll
        for (int c2 = 0; c2 < 64; ++c2)             // row i of M (coalesced)
            r[c2] = pm[h * 4096 + c2 * 64 + i];
        const float sg = sgnNZ[i];
        #pragma unroll
        for (int j = 0; j < 64; ++j) {
            const float qj = r[j] * dinv[j];
            P[h * 4096 + j * 64 + i] = qj * sg;      // P[h][e=j][f=i]
            #pragma unroll
            for (int c2 = j + 1; c2 < 64; ++c2)
                r[c2] = fmaf(-qj, Rs[j * 65 + c2], r[c2]);
        }
    }
}

// -------- FAVOR+ map: direct global->VGPR fragments, zero barriers ----------
__global__ __launch_bounds__(256, 3) void favor_kernel(const float* __restrict__ data,
                                                       const float* __restrict__ P,
                                                       float* __restrict__ out)
{
    __shared__ __attribute__((aligned(16))) float SMEM[4096];   // 4 KB/wave scratch

    const int tid   = threadIdx.x;
    const int chunk = blockIdx.x >> 4;              // 0..127
    const int h     = (blockIdx.x + chunk) & 15;    // head-derangement: every
                                                    // XCD sees all 16 offsets
    const size_t rowbase = (size_t)chunk * 512;     // 8 tiles x 64 rows

    const int lane = tid & 63;
    const int wv   = tid >> 6;                      // wave owns rows 16wv..16wv+15
    const int ls   = lane & 15;                     // A-row / C-col
    const int lg   = lane >> 4;                     // k-group

    const float* db = data + (size_t)h * 64;
    const int c0 = lg * 8;                          // lane's k-slice base col

    // A-fragment loads in MFMA lane order: lane (ls,lg) reads row ls,
    // cols c0..c0+7 (kh=0) and 32+c0..32+c0+7 (kh=1): 4x dwordx4.
#define LOADX(T, X) do {                                                           \
        const float* rp_ = db + (rowbase + (size_t)(T) * 64 + 16 * wv + ls) * 1024;\
        (X)[0] = *reinterpret_cast<const float4*>(rp_ + c0);                       \
        (X)[1] = *reinterpret_cast<const float4*>(rp_ + c0 + 4);                   \
        (X)[2] = *reinterpret_cast<const float4*>(rp_ + c0 + 32);                  \
        (X)[3] = *reinterpret_cast<const float4*>(rp_ + c0 + 36);                  \
    } while (0)

    float4 xv[4];
    LOADX(0, xv);                                   // prologue

    // B fragments straight from global (L1/L2-cached, shared by all blocks of
    // this head). B[k][col]: col = n*16 + ls, k = kh*32 + lg*8 + j.
    f16x8 bh[4][2], bl[4][2];
    #pragma unroll
    for (int n = 0; n < 4; ++n) {
        #pragma unroll
        for (int kh = 0; kh < 2; ++kh) {
            #pragma unroll
            for (int j = 0; j < 8; ++j) {
                const float pv = P[h * 4096 + (kh * 32 + lg * 8 + j) * 64 + n * 16 + ls];
                const _Float16 hi = (_Float16)pv;
                bh[n][kh][j] = hi;
                bl[n][kh][j] = (_Float16)(pv - (float)hi);
            }
        }
    }

    float* strip = SMEM + wv * 1024;                // wave-private 16x64 scratch
    const float SQS = 0.09016844005556021f;         // log2(e)/16

    #pragma unroll 1
    for (int t = 0; t < 8; ++t) {
        // ---- convert current tile regs -> A fragments + sq partial ----
        f16x8 ah[2], al[2];
        float sq = 0.f;
        #pragma unroll
        for (int kh = 0; kh < 2; ++kh) {
            const float xs[8] = {xv[2*kh].x, xv[2*kh].y, xv[2*kh].z, xv[2*kh].w,
                                 xv[2*kh+1].x, xv[2*kh+1].y, xv[2*kh+1].z, xv[2*kh+1].w};
            #pragma unroll
            for (int j = 0; j < 8; ++j) {
                const float x = xs[j];
                const _Float16 hi = (_Float16)x;
                ah[kh][j] = hi;
                al[kh][j] = (_Float16)(x - (float)hi);
                sq = fmaf(x, x, sq);
            }
        }
        // ---- issue next tile's loads (before MFMA/stores: FIFO-decoupled) ----
        if (t < 7) LOADX(t + 1, xv);

        sq += __shfl_xor(sq, 16);                   // sum over lg groups
        sq += __shfl_xor(sq, 32);                   // (valid for row ls)

        // ---- 24 MFMAs: C = Xh*Bh + Xh*Bl + Xl*Bh ----
        f32x4 acc[4];
        #pragma unroll
        for (int n = 0; n < 4; ++n) {
            f32x4 a = {0.f, 0.f, 0.f, 0.f};
            #pragma unroll
            for (int kh = 0; kh < 2; ++kh) {
                a = __builtin_amdgcn_mfma_f32_16x16x32_f16(ah[kh], bh[n][kh], a, 0, 0, 0);
                a = __builtin_amdgcn_mfma_f32_16x16x32_f16(ah[kh], bl[n][kh], a, 0, 0, 0);
                a = __builtin_amdgcn_mfma_f32_16x16x32_f16(al[kh], bh[n][kh], a, 0, 0, 0);
            }
            acc[n] = a;
        }

        // ---- epilogue: exp2+eps, transpose C through wave-private LDS strip
        //      (lgkmcnt-only sync; no barrier), then 4x NONTEMPORAL dwordx4 ----
        // write C[row][f] at strip[row*64 + ((16n+ls)^(lg<<4))]  (2-way banks)
        #pragma unroll
        for (int reg = 0; reg < 4; ++reg) {
            const int row_i = 4 * lg + reg;
            const float sqr = __shfl(sq, row_i) * SQS;   // from lane ls = row_i
            #pragma unroll
            for (int n = 0; n < 4; ++n)
                strip[row_i * 64 + ((16 * n + ls) ^ (lg << 4))] =
                    EXP2F(acc[n][reg] - sqr) + 1e-6f;
        }
        asm volatile("s_waitcnt lgkmcnt(0)" ::: "memory");   // writes visible
        // read back: lane(ls,lg), store s: row = 4s+lg, f0 = 4ls;
        // element (row,f) lives at f ^ ((row>>2)<<4) = f ^ (s<<4)
        const size_t rowT = rowbase + (size_t)t * 64 + 16 * wv;
        #pragma unroll
        for (int s = 0; s < 4; ++s) {
            const int row = 4 * s + lg;
            const f32x4 v = *reinterpret_cast<const f32x4*>(
                strip + row * 64 + ((4 * ls) ^ (s << 4)));
            __builtin_nontemporal_store(v, reinterpret_cast<f32x4*>(
                out + (rowT + (size_t)row) * 1024 + (size_t)h * 64 + 4 * ls));
        }
        asm volatile("s_waitcnt lgkmcnt(0)" ::: "memory");   // reads done before
                                                             // next iter rewrites
    }
#undef LOADX
}

extern "C" void kernel_launch(void* const* d_in, const int* in_sizes, int n_in,
                              void* d_out, int out_size, void* d_ws, size_t ws_size,
                              hipStream_t stream)
{
    const float* data = (const float*)d_in[0];   // (L,N,H,E) fp32
    const float* pm   = (const float*)d_in[1];   // (H,E,E)   fp32
    float* out = (float*)d_out;                  // (L,N,H,F) fp32
    float* P   = (float*)d_ws;                   // 16*64*64*4 = 256 KB scratch

    qr_kernel<<<16, 256, 0, stream>>>(pm, P);
    favor_kernel<<<2048, 256, 0, stream>>>(data, P, out);
}